// Round 9
// baseline (295.158 us; speedup 1.0000x reference)
//
#include <hip/hip_runtime.h>
#include <cfloat>

#define NTOK (64 * 4096)   // 262144 tokens
#define HID  128
#define NE   64
#define TK   6
#define BLK  256
#define TPB  256           // tokens per block (GEMM); epilogue in 2 half-passes
#define HTOK 128           // tokens per epilogue pass
#define GRID (NTOK / TPB)  // 1024 blocks -> 4 blocks/CU
#define LST  67            // logit row stride: odd (no b128 merge), 3 mod 32 -> <=2-way

__global__ __launch_bounds__(BLK, 4)
void gate_kernel(const float* __restrict__ X,
                 const float* __restrict__ W,
                 float* __restrict__ oidx,
                 float* __restrict__ ow,
                 float* __restrict__ Pi_g,
                 unsigned int* __restrict__ cnt_g)
{
    // Phase GEMM : smem[0..8192)  = W rotated: Wlds[k][(e + 4*((k>>2)&15)) & 63]
    // Phase EPI h: smem[0..8576)  = logits L[lt][e] at lt*LST+e, lt = token-128h
    __shared__ float        smem[HTOK * LST];   // 34.3 KB (covers 32 KB W region)
    __shared__ float        mz[2 * TPB];
    __shared__ float        Pi_s[NE];
    __shared__ unsigned int cnt_s[NE];

    const int tid  = threadIdx.x;
    const int lane = tid & 63;
    const int wv   = __builtin_amdgcn_readfirstlane(tid >> 6);  // 0..3
    const int eb   = wv * 16;                  // this wave's 16 experts

    if (tid < NE) cnt_s[tid] = 0u;

    // ---- stage W rotated (one-time)
    {
        const float4* W4 = (const float4*)W;
#pragma unroll
        for (int i = 0; i < 8; ++i) {
            const int flat = tid + i * BLK;     // [0,2048) float4 index
            const float4 v = W4[flat];
            const int e   = flat >> 5;
            const int c   = flat & 31;          // k>>2
            const int col = (e + ((c & 15) << 2)) & 63;
            float* p = &smem[c * 256 + col];    // k rows 4c..4c+3
            p[0]   = v.x;
            p[64]  = v.y;
            p[128] = v.z;
            p[192] = v.w;
        }
    }
    __syncthreads();

    const int gtok0 = blockIdx.x * TPB;
    const float4* xr0 = (const float4*)(X + (size_t)(gtok0 + lane      ) * HID);
    const float4* xr1 = (const float4*)(X + (size_t)(gtok0 + lane +  64) * HID);
    const float4* xr2 = (const float4*)(X + (size_t)(gtok0 + lane + 128) * HID);
    const float4* xr3 = (const float4*)(X + (size_t)(gtok0 + lane + 192) * HID);

    float acc[4][16];
#pragma unroll
    for (int g = 0; g < 4; ++g)
#pragma unroll
        for (int j = 0; j < 16; ++j) acc[g][j] = 0.0f;

    // ---- GEMM: wave computes 16 experts x 256 tokens (4 tokens/lane)
#pragma unroll 2
    for (int c = 0; c < 32; ++c) {             // k = 4c..4c+3
        float xs[4][4];
        {
            const float4 v0 = xr0[c], v1 = xr1[c], v2 = xr2[c], v3 = xr3[c];
            xs[0][0]=v0.x; xs[0][1]=v0.y; xs[0][2]=v0.z; xs[0][3]=v0.w;
            xs[1][0]=v1.x; xs[1][1]=v1.y; xs[1][2]=v1.z; xs[1][3]=v1.w;
            xs[2][0]=v2.x; xs[2][1]=v2.y; xs[2][2]=v2.z; xs[2][3]=v2.w;
            xs[3][0]=v3.x; xs[3][1]=v3.y; xs[3][2]=v3.z; xs[3][3]=v3.w;
        }
        const int rr = (c & 15) << 2;
        const int c0 = (eb +  0 + rr) & 63;
        const int c1 = (eb +  4 + rr) & 63;
        const int c2 = (eb +  8 + rr) & 63;
        const int c3 = (eb + 12 + rr) & 63;
        const float* rowb = &smem[c * 256];
#pragma unroll
        for (int d = 0; d < 4; ++d) {
            const float* row = rowb + d * 64;
            const float4 w0 = *(const float4*)&row[c0];   // uniform: no conflicts
            const float4 w1 = *(const float4*)&row[c1];
            const float4 w2 = *(const float4*)&row[c2];
            const float4 w3 = *(const float4*)&row[c3];
#pragma unroll
            for (int g = 0; g < 4; ++g) {
                const float xv = xs[g][d];
                acc[g][ 0] = fmaf(xv, w0.x, acc[g][ 0]);
                acc[g][ 1] = fmaf(xv, w0.y, acc[g][ 1]);
                acc[g][ 2] = fmaf(xv, w0.z, acc[g][ 2]);
                acc[g][ 3] = fmaf(xv, w0.w, acc[g][ 3]);
                acc[g][ 4] = fmaf(xv, w1.x, acc[g][ 4]);
                acc[g][ 5] = fmaf(xv, w1.y, acc[g][ 5]);
                acc[g][ 6] = fmaf(xv, w1.z, acc[g][ 6]);
                acc[g][ 7] = fmaf(xv, w1.w, acc[g][ 7]);
                acc[g][ 8] = fmaf(xv, w2.x, acc[g][ 8]);
                acc[g][ 9] = fmaf(xv, w2.y, acc[g][ 9]);
                acc[g][10] = fmaf(xv, w2.z, acc[g][10]);
                acc[g][11] = fmaf(xv, w2.w, acc[g][11]);
                acc[g][12] = fmaf(xv, w3.x, acc[g][12]);
                acc[g][13] = fmaf(xv, w3.y, acc[g][13]);
                acc[g][14] = fmaf(xv, w3.z, acc[g][14]);
                acc[g][15] = fmaf(xv, w3.w, acc[g][15]);
            }
        }
    }

    __syncthreads();   // all waves done reading W -> tile region reusable

    float pi[16];
#pragma unroll
    for (int j = 0; j < 16; ++j) pi[j] = 0.0f;

    // ---- two half-tile passes over tokens [128h, 128h+128)
#pragma unroll 1
    for (int h = 0; h < 2; ++h) {
        // scatter this half's logits: L[lt][e] = smem[lt*67 + e]
        // (acc groups 2h, 2h+1 die here -> register pressure drops)
#pragma unroll
        for (int g2 = 0; g2 < 2; ++g2) {
            const int g  = 2*h + g2;
            const int lt = lane + 64 * g2;
            float* p = &smem[lt * LST + eb];
#pragma unroll
            for (int j = 0; j < 16; ++j) p[j] = acc[g][j];
        }
        __syncthreads();

        // thread = token for this half (128 threads active)
        if ((tid >> 7) == h) {
            const int lt = tid - 128 * h;
            const int t  = tid;                 // block-local token
            const float* Lrow = &smem[lt * LST];
            float tv[TK]; int ti[TK];
#pragma unroll
            for (int q = 0; q < TK; ++q) { tv[q] = -FLT_MAX; ti[q] = 0; }

#pragma unroll 8
            for (int e = 0; e < NE; ++e) {     // ascending e: jax stable tie order
                float m = Lrow[e];             // b32, <=2-way by stride design
                int   mi = e;
#pragma unroll
                for (int q = 0; q < TK; ++q) {
                    const bool  cx = m > tv[q];
                    const float nt = cx ? m     : tv[q];
                    const float nm = cx ? tv[q] : m;
                    const int   ni = cx ? mi    : ti[q];
                    const int   nj = cx ? ti[q] : mi;
                    tv[q] = nt; m = nm; ti[q] = ni; mi = nj;
                }
            }

            const float mx = tv[0];
            float ex[TK]; float s = 0.0f;
#pragma unroll
            for (int q = 0; q < TK; ++q) { ex[q] = __expf(tv[q] - mx); s += ex[q]; }
            const float rs = 1.0f / (s + 1e-20f);

            const size_t gt = (size_t)(gtok0 + t) * TK;
            float2* ip = (float2*)(oidx + gt);
            float2* wp = (float2*)(ow + gt);
            ip[0] = make_float2((float)ti[0], (float)ti[1]);
            ip[1] = make_float2((float)ti[2], (float)ti[3]);
            ip[2] = make_float2((float)ti[4], (float)ti[5]);
            wp[0] = make_float2(ex[0]*rs, ex[1]*rs);
            wp[1] = make_float2(ex[2]*rs, ex[3]*rs);
            wp[2] = make_float2(ex[4]*rs, ex[5]*rs);

#pragma unroll
            for (int q = 0; q < TK; ++q) atomicAdd(&cnt_s[ti[q]], 1u);

            float Z = 0.0f;
#pragma unroll 8
            for (int e = 0; e < NE; ++e) Z += __expf(Lrow[e] - mx);
            mz[2*t]     = mx;
            mz[2*t + 1] = 1.0f / Z;
        }
        __syncthreads();   // mz ready; tile still holds this half's logits

        // Pi partials from the tile: 2 tokens/lane x wave's 16 experts
#pragma unroll
        for (int g2 = 0; g2 < 2; ++g2) {
            const int lt = lane + 64 * g2;
            const int t  = 128 * h + lt;
            const float mxt = mz[2*t];
            const float rzt = mz[2*t + 1];
            const float* p = &smem[lt * LST + eb];
#pragma unroll
            for (int j = 0; j < 16; ++j)
                pi[j] += __expf(p[j] - mxt) * rzt;
        }
        __syncthreads();   // done reading tile before next scatter
    }

    // butterfly: every lane ends with the wave-total for each of the 16 experts
#pragma unroll
    for (int s = 1; s <= 32; s <<= 1) {
#pragma unroll
        for (int j = 0; j < 16; ++j) pi[j] += __shfl_xor(pi[j], s);
    }
    if (lane < 16) Pi_s[eb + lane] = pi[lane];   // waves own disjoint experts
    __syncthreads();

    if (tid < NE) {
        atomicAdd(&Pi_g[tid], Pi_s[tid]);
        atomicAdd(&cnt_g[tid], cnt_s[tid]);
    }
}

__global__ void aux_kernel(const float* __restrict__ Pi_g,
                           const unsigned int* __restrict__ cnt_g,
                           float* __restrict__ out_aux)
{
    const int e = threadIdx.x;   // 64 threads
    const float Pi = Pi_g[e] * (1.0f / (float)NTOK);
    const float ce = (float)cnt_g[e] * (1.0f / (float)(NTOK * TK));
    float v = Pi * ce * (float)NE;
#pragma unroll
    for (int off = 32; off > 0; off >>= 1) v += __shfl_down(v, off);
    if (e == 0) out_aux[0] = v * 1.0e-3f;
}

extern "C" void kernel_launch(void* const* d_in, const int* in_sizes, int n_in,
                              void* d_out, int out_size, void* d_ws, size_t ws_size,
                              hipStream_t stream) {
    const float* X = (const float*)d_in[0];
    const float* W = (const float*)d_in[1];

    float* out  = (float*)d_out;
    float* oidx = out;                          // N*6 indices (as float)
    float* ow   = out + (size_t)NTOK * TK;      // N*6 weights
    float* aux  = out + (size_t)NTOK * TK * 2;  // 1 scalar

    float*        Pi_g  = (float*)d_ws;
    unsigned int* cnt_g = (unsigned int*)((char*)d_ws + 256);

    hipMemsetAsync(d_ws, 0, 512, stream);
    gate_kernel<<<GRID, BLK, 0, stream>>>(X, W, oidx, ow, Pi_g, cnt_g);
    aux_kernel<<<1, 64, 0, stream>>>(Pi_g, cnt_g, aux);
}

// Round 10
// 262.656 us; speedup vs baseline: 1.1237x; 1.1237x over previous
//
#include <hip/hip_runtime.h>
#include <cfloat>

#define NTOK (64 * 4096)   // 262144 tokens
#define HID  128
#define NE   64
#define TK   6
#define BLK  256
#define TPB  256           // tokens per block (GEMM); epilogue in 2 half-passes
#define HTOK 128           // tokens per epilogue pass
#define GRID (NTOK / TPB)  // 1024 blocks -> 4 blocks/CU
#define LST  67            // logit row stride: odd (no b128 merge), 3 mod 32 -> <=2-way

__global__ __launch_bounds__(BLK, 4)
void gate_kernel(const float* __restrict__ X,
                 const float* __restrict__ W,
                 float* __restrict__ oidx,
                 float* __restrict__ ow,
                 float* __restrict__ Pi_g,
                 unsigned int* __restrict__ cnt_g)
{
    // Phase GEMM : smem[0..8192)  = W rotated: Wlds[k][(e + 4*((k>>2)&15)) & 63]
    // Phase EPI h: smem[0..8576)  = logits L[lt][e] at lt*LST+e, lt = token-128h
    __shared__ float        smem[HTOK * LST];   // 34.3 KB (covers 32 KB W region)
    __shared__ float        mz[2 * TPB];
    __shared__ float        Pi_s[NE];
    __shared__ unsigned int cnt_s[NE];

    const int tid  = threadIdx.x;
    const int lane = tid & 63;
    const int wv   = __builtin_amdgcn_readfirstlane(tid >> 6);  // 0..3
    const int eb   = wv * 16;                  // this wave's 16 experts

    if (tid < NE) cnt_s[tid] = 0u;

    // ---- stage W rotated (one-time)
    {
        const float4* W4 = (const float4*)W;
#pragma unroll
        for (int i = 0; i < 8; ++i) {
            const int flat = tid + i * BLK;     // [0,2048) float4 index
            const float4 v = W4[flat];
            const int e   = flat >> 5;
            const int c   = flat & 31;          // k>>2
            const int col = (e + ((c & 15) << 2)) & 63;
            float* p = &smem[c * 256 + col];    // k rows 4c..4c+3
            p[0]   = v.x;
            p[64]  = v.y;
            p[128] = v.z;
            p[192] = v.w;
        }
    }
    __syncthreads();

    const int gtok0 = blockIdx.x * TPB;
    const float4* xr0 = (const float4*)(X + (size_t)(gtok0 + lane      ) * HID);
    const float4* xr1 = (const float4*)(X + (size_t)(gtok0 + lane +  64) * HID);
    const float4* xr2 = (const float4*)(X + (size_t)(gtok0 + lane + 128) * HID);
    const float4* xr3 = (const float4*)(X + (size_t)(gtok0 + lane + 192) * HID);

    float acc[4][16];
#pragma unroll
    for (int g = 0; g < 4; ++g)
#pragma unroll
        for (int j = 0; j < 16; ++j) acc[g][j] = 0.0f;

    // ---- GEMM: wave computes 16 experts x 256 tokens (4 tokens/lane)
#pragma unroll 2
    for (int c = 0; c < 32; ++c) {             // k = 4c..4c+3
        float xs[4][4];
        {
            const float4 v0 = xr0[c], v1 = xr1[c], v2 = xr2[c], v3 = xr3[c];
            xs[0][0]=v0.x; xs[0][1]=v0.y; xs[0][2]=v0.z; xs[0][3]=v0.w;
            xs[1][0]=v1.x; xs[1][1]=v1.y; xs[1][2]=v1.z; xs[1][3]=v1.w;
            xs[2][0]=v2.x; xs[2][1]=v2.y; xs[2][2]=v2.z; xs[2][3]=v2.w;
            xs[3][0]=v3.x; xs[3][1]=v3.y; xs[3][2]=v3.z; xs[3][3]=v3.w;
        }
        const int rr = (c & 15) << 2;
        const int c0 = (eb +  0 + rr) & 63;
        const int c1 = (eb +  4 + rr) & 63;
        const int c2 = (eb +  8 + rr) & 63;
        const int c3 = (eb + 12 + rr) & 63;
        const float* rowb = &smem[c * 256];
#pragma unroll
        for (int d = 0; d < 4; ++d) {
            const float* row = rowb + d * 64;
            const float4 w0 = *(const float4*)&row[c0];   // uniform: no conflicts
            const float4 w1 = *(const float4*)&row[c1];
            const float4 w2 = *(const float4*)&row[c2];
            const float4 w3 = *(const float4*)&row[c3];
#pragma unroll
            for (int g = 0; g < 4; ++g) {
                const float xv = xs[g][d];
                acc[g][ 0] = fmaf(xv, w0.x, acc[g][ 0]);
                acc[g][ 1] = fmaf(xv, w0.y, acc[g][ 1]);
                acc[g][ 2] = fmaf(xv, w0.z, acc[g][ 2]);
                acc[g][ 3] = fmaf(xv, w0.w, acc[g][ 3]);
                acc[g][ 4] = fmaf(xv, w1.x, acc[g][ 4]);
                acc[g][ 5] = fmaf(xv, w1.y, acc[g][ 5]);
                acc[g][ 6] = fmaf(xv, w1.z, acc[g][ 6]);
                acc[g][ 7] = fmaf(xv, w1.w, acc[g][ 7]);
                acc[g][ 8] = fmaf(xv, w2.x, acc[g][ 8]);
                acc[g][ 9] = fmaf(xv, w2.y, acc[g][ 9]);
                acc[g][10] = fmaf(xv, w2.z, acc[g][10]);
                acc[g][11] = fmaf(xv, w2.w, acc[g][11]);
                acc[g][12] = fmaf(xv, w3.x, acc[g][12]);
                acc[g][13] = fmaf(xv, w3.y, acc[g][13]);
                acc[g][14] = fmaf(xv, w3.z, acc[g][14]);
                acc[g][15] = fmaf(xv, w3.w, acc[g][15]);
            }
        }
    }

    __syncthreads();   // all waves done reading W -> tile region reusable

    float pi[16];
#pragma unroll
    for (int j = 0; j < 16; ++j) pi[j] = 0.0f;

    // ---- two half-tile passes, FULLY UNROLLED so every acc index is
    //      compile-time (dynamic indexing demotes acc to scratch: R8/R9 bug)
#pragma unroll
    for (int h = 0; h < 2; ++h) {
        // scatter this half's logits: L[lt][e] = smem[lt*67 + e]
        // (acc groups 2h, 2h+1 die here -> register pressure drops)
#pragma unroll
        for (int g2 = 0; g2 < 2; ++g2) {
            const int lt = lane + 64 * g2;
            float* p = &smem[lt * LST + eb];
#pragma unroll
            for (int j = 0; j < 16; ++j) p[j] = acc[2*h + g2][j];
        }
        __syncthreads();

        // thread = token for this half (128 threads active)
        if ((tid >> 7) == h) {
            const int lt = tid - 128 * h;
            const int t  = tid;                 // block-local token
            const float* Lrow = &smem[lt * LST];
            float tv[TK]; int ti[TK];
#pragma unroll
            for (int q = 0; q < TK; ++q) { tv[q] = -FLT_MAX; ti[q] = 0; }

#pragma unroll 8
            for (int e = 0; e < NE; ++e) {     // ascending e: jax stable tie order
                float m = Lrow[e];             // b32, <=2-way by stride design
                int   mi = e;
#pragma unroll
                for (int q = 0; q < TK; ++q) {
                    const bool  cx = m > tv[q];
                    const float nt = cx ? m     : tv[q];
                    const float nm = cx ? tv[q] : m;
                    const int   ni = cx ? mi    : ti[q];
                    const int   nj = cx ? ti[q] : mi;
                    tv[q] = nt; m = nm; ti[q] = ni; mi = nj;
                }
            }

            const float mx = tv[0];
            float ex[TK]; float s = 0.0f;
#pragma unroll
            for (int q = 0; q < TK; ++q) { ex[q] = __expf(tv[q] - mx); s += ex[q]; }
            const float rs = 1.0f / (s + 1e-20f);

            const size_t gt = (size_t)(gtok0 + t) * TK;
            float2* ip = (float2*)(oidx + gt);
            float2* wp = (float2*)(ow + gt);
            ip[0] = make_float2((float)ti[0], (float)ti[1]);
            ip[1] = make_float2((float)ti[2], (float)ti[3]);
            ip[2] = make_float2((float)ti[4], (float)ti[5]);
            wp[0] = make_float2(ex[0]*rs, ex[1]*rs);
            wp[1] = make_float2(ex[2]*rs, ex[3]*rs);
            wp[2] = make_float2(ex[4]*rs, ex[5]*rs);

#pragma unroll
            for (int q = 0; q < TK; ++q) atomicAdd(&cnt_s[ti[q]], 1u);

            float Z = 0.0f;
#pragma unroll 8
            for (int e = 0; e < NE; ++e) Z += __expf(Lrow[e] - mx);
            mz[2*t]     = mx;
            mz[2*t + 1] = 1.0f / Z;
        }
        __syncthreads();   // mz ready; tile still holds this half's logits

        // Pi partials from the tile: 2 tokens/lane x wave's 16 experts
#pragma unroll
        for (int g2 = 0; g2 < 2; ++g2) {
            const int lt = lane + 64 * g2;
            const int t  = 128 * h + lt;
            const float mxt = mz[2*t];
            const float rzt = mz[2*t + 1];
            const float* p = &smem[lt * LST + eb];
#pragma unroll
            for (int j = 0; j < 16; ++j)
                pi[j] += __expf(p[j] - mxt) * rzt;
        }
        __syncthreads();   // done reading tile before next scatter
    }

    // butterfly: every lane ends with the wave-total for each of the 16 experts
#pragma unroll
    for (int s = 1; s <= 32; s <<= 1) {
#pragma unroll
        for (int j = 0; j < 16; ++j) pi[j] += __shfl_xor(pi[j], s);
    }
    if (lane < 16) Pi_s[eb + lane] = pi[lane];   // waves own disjoint experts
    __syncthreads();

    if (tid < NE) {
        atomicAdd(&Pi_g[tid], Pi_s[tid]);
        atomicAdd(&cnt_g[tid], cnt_s[tid]);
    }
}

__global__ void aux_kernel(const float* __restrict__ Pi_g,
                           const unsigned int* __restrict__ cnt_g,
                           float* __restrict__ out_aux)
{
    const int e = threadIdx.x;   // 64 threads
    const float Pi = Pi_g[e] * (1.0f / (float)NTOK);
    const float ce = (float)cnt_g[e] * (1.0f / (float)(NTOK * TK));
    float v = Pi * ce * (float)NE;
#pragma unroll
    for (int off = 32; off > 0; off >>= 1) v += __shfl_down(v, off);
    if (e == 0) out_aux[0] = v * 1.0e-3f;
}

extern "C" void kernel_launch(void* const* d_in, const int* in_sizes, int n_in,
                              void* d_out, int out_size, void* d_ws, size_t ws_size,
                              hipStream_t stream) {
    const float* X = (const float*)d_in[0];
    const float* W = (const float*)d_in[1];

    float* out  = (float*)d_out;
    float* oidx = out;                          // N*6 indices (as float)
    float* ow   = out + (size_t)NTOK * TK;      // N*6 weights
    float* aux  = out + (size_t)NTOK * TK * 2;  // 1 scalar

    float*        Pi_g  = (float*)d_ws;
    unsigned int* cnt_g = (unsigned int*)((char*)d_ws + 256);

    hipMemsetAsync(d_ws, 0, 512, stream);
    gate_kernel<<<GRID, BLK, 0, stream>>>(X, W, oidx, ow, Pi_g, cnt_g);
    aux_kernel<<<1, 64, 0, stream>>>(Pi_g, cnt_g, aux);
}